// Round 9
// baseline (644.236 us; speedup 1.0000x reference)
//
#include <hip/hip_runtime.h>

// ---------- types ----------
typedef __attribute__((ext_vector_type(8))) short bf16x8;
typedef __attribute__((ext_vector_type(4))) float f32x4;

static __device__ __forceinline__ unsigned short f2bf(float x) {
    unsigned int u = __float_as_uint(x);
    u += 0x7fffu + ((u >> 16) & 1u);   // RTNE, finite inputs
    return (unsigned short)(u >> 16);
}

static __device__ __forceinline__ float selq(const f32x4* a, int q) {
    return (q == 0) ? a[0][0] : (q == 1) ? a[1][0] : (q == 2) ? a[2][0] : a[3][0];
}

// Workgroup barrier WITHOUT vmcnt drain: LDS ordering only.
static __device__ __forceinline__ void barrier_lds_only() {
    __asm__ volatile("s_waitcnt lgkmcnt(0)\n\ts_barrier" ::: "memory");
}

// ---------- K0: four fp32->bf16 transposes in one launch ----------
__global__ void transpose4(const float* __restrict__ s0, const float* __restrict__ s1,
                           const float* __restrict__ s2, const float* __restrict__ s3,
                           unsigned short* __restrict__ d0, unsigned short* __restrict__ d1,
                           unsigned short* __restrict__ d2, unsigned short* __restrict__ d3) {
    int which = blockIdx.y;
    const float* src = which == 0 ? s0 : which == 1 ? s1 : which == 2 ? s2 : s3;
    unsigned short* dst = which == 0 ? d0 : which == 1 ? d1 : which == 2 ? d2 : d3;
    int K = (which == 0) ? 512 : 256;
    int idx = blockIdx.x * 256 + threadIdx.x;
    if (idx >= K * 256) return;
    int k = idx >> 8;          // N = 256
    int n = idx & 255;
    dst[n * K + k] = f2bf(src[idx]);
}

// ---------- K1 GEMM: C[M,N] = A[M,K] @ Bt[N,K]^T + bias, bf16 MFMA ----------
// (r7/r8-passing version: gather hoisted, next-tile prefetch under MFMAs)
template<bool GATHER>
__global__ __launch_bounds__(256, 4) void gemm_mfma(
    const void* __restrict__ Aptr, const int* __restrict__ tokens,
    const unsigned short* __restrict__ Bt, const float* __restrict__ bias,
    float* __restrict__ C, int M, int N, int K)
{
    const int bn0 = blockIdx.x * 64;
    const int m0  = blockIdx.y * 64;
    const int tid = threadIdx.x;

    __shared__ unsigned short As[64 * 40];
    __shared__ unsigned short Bs[64 * 40];
    __shared__ int tok[64];

    const int r  = tid >> 2;
    const int c0 = (tid & 3) * 8;
    const int w  = tid >> 6;
    const int L  = tid & 63;
    const int ml = L & 15;
    const int q  = L >> 4;
    const int kq = q * 8;

    if (GATHER) {
        if (tid < 64) tok[tid] = tokens[m0 + tid];
        __syncthreads();
    }

    const float* af32 = nullptr;
    const unsigned short* abf = nullptr;
    if (GATHER) af32 = (const float*)Aptr + (size_t)tok[r] * K + c0;
    else        abf  = (const unsigned short*)Aptr + (size_t)(m0 + r) * K + c0;
    const unsigned short* bsrc = Bt + (size_t)(bn0 + r) * K + c0;

    float4 f0, f1; uint4 ab, bb;
    if (GATHER) { f0 = *(const float4*)af32; f1 = *(const float4*)(af32 + 4); af32 += 32; }
    else        { ab = *(const uint4*)abf; abf += 32; }
    bb = *(const uint4*)bsrc; bsrc += 32;

    f32x4 acc[4] = {};

    for (int k0 = 0; k0 < K; k0 += 32) {
        unsigned short tmp[8];
        if (GATHER) {
            tmp[0]=f2bf(f0.x); tmp[1]=f2bf(f0.y); tmp[2]=f2bf(f0.z); tmp[3]=f2bf(f0.w);
            tmp[4]=f2bf(f1.x); tmp[5]=f2bf(f1.y); tmp[6]=f2bf(f1.z); tmp[7]=f2bf(f1.w);
        } else {
            *(uint4*)tmp = ab;
        }
        *(uint4*)&As[r * 40 + c0] = *(const uint4*)tmp;
        *(uint4*)&Bs[r * 40 + c0] = bb;
        __syncthreads();

        if (k0 + 32 < K) {
            if (GATHER) { f0 = *(const float4*)af32; f1 = *(const float4*)(af32 + 4); af32 += 32; }
            else        { ab = *(const uint4*)abf; abf += 32; }
            bb = *(const uint4*)bsrc; bsrc += 32;
        }

        bf16x8 av = *(const bf16x8*)&As[(16 * w + ml) * 40 + kq];
#pragma unroll
        for (int ns = 0; ns < 4; ++ns) {
            bf16x8 bv = *(const bf16x8*)&Bs[(ns * 16 + ml) * 40 + kq];
            acc[ns] = __builtin_amdgcn_mfma_f32_16x16x32_bf16(av, bv, acc[ns], 0, 0, 0);
        }
        __syncthreads();
    }

#pragma unroll
    for (int ns = 0; ns < 4; ++ns) {
        int gn = bn0 + ns * 16 + ml;
        float bv = bias[gn];
#pragma unroll
        for (int rr = 0; rr < 4; ++rr) {
            int gm = m0 + 16 * w + q * 4 + rr;
            C[(size_t)gm * N + gn] = acc[ns][rr] + bv;
        }
    }
}

// ---------- K2: cross-CU pipeline with STACKED-MATRIX consumer (p eliminated) ----
// 96 blocks x 512 threads.
// Producer blocks 0..31: TWO independent baseline scan1s per block (waves 0-3 ->
//   batch 2b, waves 4-7 -> batch 2b+1; one U1f set per wave; 2 waves/SIMD).
//   h1[t] bf16 -> global h1g. Per 8 ticks: per-wave vmcnt(0) drain -> s_barrier ->
//   RELEASE flags[2b] (tid 0) and flags[2b+1] (tid 256)  [r4-proven mechanism].
// Consumer blocks 32..95 (batch b = bid-32): h2[t] = tanh([h1[t],h2[t-1]] @
//   [W2;U2] + b2) -- ONE 512-K matvec, no intermediate p, no GEMV, no bank
//   conflicts. 8 waves x 2 n-tiles x 16 k-tiles = 128-reg stacked fragment set
//   per wave (register rule holds at 2 waves/SIMD). h1[t+1] staged from global
//   (L3-hot) with a 1-tick register prefetch; gated 2 flag-groups behind.
// All spins bounded -> coherence failure = wrong answer, never a hang.
__global__ __launch_bounds__(512) void rnn_pipe2(
    const float* __restrict__ xw,             // [64][512][256] f32 (= emb@W1+b1)
    const unsigned short* __restrict__ U1t,   // [256][256] bf16 [n][k]
    const unsigned short* __restrict__ W2t,   // [256][256] bf16 [n][k]
    const unsigned short* __restrict__ U2t,   // [256][256] bf16 [n][k]
    const float* __restrict__ b2,             // [256]
    unsigned short* h1g,                      // [64][512][256] bf16 (+pad row)
    int* flags,                               // [64], zeroed before launch
    float* __restrict__ out_last)             // [64][256] f32
{
    const int bid = blockIdx.x;
    const int tid = threadIdx.x;
    const int w   = tid >> 6;       // 0..7
    const int L   = tid & 63;
    const int q   = L >> 4;
    const int ml  = L & 15;

    __shared__ unsigned short smem[2048];   // producer: hsh[2][2][256]; consumer: cat[2][512]

    if (bid < 32) {
        // ================= producer: 2 batches, r4-proven scan =================
        const int half = w >> 2;            // 0: batch 2b, 1: batch 2b+1
        const int rw   = w & 3;
        const int b    = 2 * bid + half;
        const int colh = rw * 64 + L;       // column within this batch
        unsigned short* hsh = smem + half * 512;   // hsh[half][parity][256] -> +parity*256

        bf16x8 U1f[4][8];
#pragma unroll
        for (int i = 0; i < 4; ++i) {
            const unsigned short* up = U1t + (size_t)((rw * 4 + i) * 16 + ml) * 256 + q * 8;
#pragma unroll
            for (int kt = 0; kt < 8; ++kt)
                U1f[i][kt] = *(const bf16x8*)(up + kt * 32);
        }
        hsh[0 * 256 + colh] = 0;            // h1[-1] = 0

        const float* xpf = xw + (size_t)b * 512 * 256 + colh;
        float xq0 = xpf[0], xq1 = xpf[256], xq2 = xpf[512], xq3 = xpf[768];
        xpf += 4 * 256;
        unsigned short* op = h1g + (size_t)b * 512 * 256 + colh;
        __syncthreads();

#define PSTEP(CUR, XQ)                                                               \
    {                                                                                \
        bf16x8 af[8];                                                                \
        _Pragma("unroll")                                                            \
        for (int kt = 0; kt < 8; ++kt)                                               \
            af[kt] = *(const bf16x8*)&hsh[(CUR) * 256 + kt * 32 + q * 8];            \
        float xnew = *xpf; xpf += 256;      /* unconditional; tail overreads ws */   \
        f32x4 accA[4] = {}, accB[4] = {};                                            \
        _Pragma("unroll")                                                            \
        for (int kt = 0; kt < 8; kt += 2) {                                          \
            _Pragma("unroll")                                                        \
            for (int i = 0; i < 4; ++i)                                              \
                accA[i] = __builtin_amdgcn_mfma_f32_16x16x32_bf16(af[kt], U1f[i][kt], accA[i], 0, 0, 0);       \
            _Pragma("unroll")                                                        \
            for (int i = 0; i < 4; ++i)                                              \
                accB[i] = __builtin_amdgcn_mfma_f32_16x16x32_bf16(af[kt + 1], U1f[i][kt + 1], accB[i], 0, 0, 0); \
        }                                                                            \
        float z  = selq(accA, q) + selq(accB, q) + XQ;                               \
        float e  = __expf(2.f * z);         /* tanh(z) = 1 - 2/(e^{2z}+1) */         \
        float hn = 1.f - 2.f * __builtin_amdgcn_rcpf(e + 1.f);                       \
        unsigned short hb = f2bf(hn);                                                \
        hsh[((CUR) ^ 1) * 256 + colh] = hb;                                          \
        *op = hb; op += 256;                                                         \
        XQ = xnew;                                                                   \
        barrier_lds_only();                                                          \
    }

        for (int g = 0; g < 64; ++g) {      // ticks 8g..8g+7
            PSTEP(0, xq0) PSTEP(1, xq1) PSTEP(0, xq2) PSTEP(1, xq3)
            PSTEP(0, xq0) PSTEP(1, xq1) PSTEP(0, xq2) PSTEP(1, xq3)
            asm volatile("s_waitcnt vmcnt(0)" ::: "memory");
            __builtin_amdgcn_s_barrier();
            if (tid == 0)
                __hip_atomic_store(flags + 2 * bid,     8 * g + 8, __ATOMIC_RELEASE, __HIP_MEMORY_SCOPE_AGENT);
            if (tid == 256)
                __hip_atomic_store(flags + 2 * bid + 1, 8 * g + 8, __ATOMIC_RELEASE, __HIP_MEMORY_SCOPE_AGENT);
        }
#undef PSTEP

    } else {
        // ================= consumer: stacked [W2;U2] scan2 =================
        const int b = bid - 32;
        int* flagp = flags + b;
        unsigned short* cat = smem;          // cat[parity][512]: [0..255]=h1, [256..511]=h2

        // stacked fragments: n-tiles w*2+i (i=0,1); kt 0..7 -> W2, kt 8..15 -> U2
        bf16x8 Bf[2][16];
#pragma unroll
        for (int i = 0; i < 2; ++i) {
            const int n = (w * 2 + i) * 16 + ml;
            const unsigned short* w2 = W2t + (size_t)n * 256 + q * 8;
            const unsigned short* u2 = U2t + (size_t)n * 256 + q * 8;
#pragma unroll
            for (int kt = 0; kt < 8; ++kt) {
                Bf[i][kt]     = *(const bf16x8*)(w2 + kt * 32);
                Bf[i][8 + kt] = *(const bf16x8*)(u2 + kt * 32);
            }
        }
        const int  col2 = w * 32 + (q & 1) * 16 + ml;   // owned output column (q<2 lanes)
        const bool own  = (q < 2);
        const float b2c = b2[col2];
        if (tid < 256) cat[0 * 512 + 256 + tid] = 0;    // h2[-1] = 0
        const unsigned short* h1p = h1g + (size_t)b * 512 * 256;
        float lastv = 0.f;
        __syncthreads();

        for (int c = 0; c < 64; ++c) {
            // gate 2 flag-groups ahead: rows <= 8c+15 ready -> covers reads 8c..8c+7
            // and stages 8c+1..8c+8
            if (tid == 0) {
                const int need = (c < 62) ? 8 * c + 16 : 512;
                int it = 0;   // bounded spin
                while (__hip_atomic_load(flagp, __ATOMIC_ACQUIRE, __HIP_MEMORY_SCOPE_AGENT) < need) {
                    __builtin_amdgcn_s_sleep(2);
                    if (++it > (1 << 17)) break;
                }
            }
            __syncthreads();
            if (c == 0) {   // initial stage: h1[0] -> cat[0][0..255]
                if (tid < 64) {
                    ushort4 v = *(const ushort4*)(h1p + tid * 4);
                    *(ushort4*)&cat[0 * 512 + tid * 4] = v;
                }
                barrier_lds_only();
            }
#pragma unroll
            for (int j = 0; j < 8; ++j) {
                const int t  = 8 * c + j;
                const int RP = t & 1;
                // prefetch h1[t+1] (register; LDS write at tick end). Row 512 -> pad.
                ushort4 hv;
                if (tid < 64)
                    hv = *(const ushort4*)(h1p + ((size_t)(t + 1) << 8) + tid * 4);
                bf16x8 af1[8], af2[8];
#pragma unroll
                for (int kt = 0; kt < 8; ++kt) {
                    af1[kt] = *(const bf16x8*)&cat[RP * 512 + kt * 32 + q * 8];        // h1[t]
                    af2[kt] = *(const bf16x8*)&cat[RP * 512 + 256 + kt * 32 + q * 8];  // h2[t-1]
                }
                f32x4 cA[2] = {}, cB[2] = {};
#pragma unroll
                for (int kt = 0; kt < 8; ++kt) {
#pragma unroll
                    for (int i = 0; i < 2; ++i)
                        cA[i] = __builtin_amdgcn_mfma_f32_16x16x32_bf16(af1[kt], Bf[i][kt], cA[i], 0, 0, 0);
#pragma unroll
                    for (int i = 0; i < 2; ++i)
                        cB[i] = __builtin_amdgcn_mfma_f32_16x16x32_bf16(af2[kt], Bf[i][8 + kt], cB[i], 0, 0, 0);
                }
                float z  = ((q & 1) == 0 ? cA[0][0] + cB[0][0] : cA[1][0] + cB[1][0]) + b2c;
                float e  = __expf(2.f * z);
                float hn = 1.f - 2.f * __builtin_amdgcn_rcpf(e + 1.f);
                if (own) {
                    lastv = hn;
                    cat[(RP ^ 1) * 512 + 256 + col2] = f2bf(hn);
                }
                if (tid < 64)
                    *(ushort4*)&cat[(RP ^ 1) * 512 + tid * 4] = hv;
                barrier_lds_only();
            }
        }

        if (own) out_last[b * 256 + col2] = lastv;
    }
}

// ---------- head: softmax(h2 @ Wd + bd) ----------
__global__ void head_kernel(const float* __restrict__ h2, const float* __restrict__ Wd,
                            const float* __restrict__ bd, float* __restrict__ out)
{
    int tid = threadIdx.x;         // 128 threads: b = tid>>1, c = tid&1
    int b = tid >> 1, c = tid & 1;
    float s = bd[c];
    for (int jj = 0; jj < 256; ++jj) s = fmaf(h2[b * 256 + jj], Wd[jj * 2 + c], s);
    __shared__ float lg[128];
    lg[tid] = s;
    __syncthreads();
    float o0 = lg[b * 2 + 0], o1 = lg[b * 2 + 1];
    float m = fmaxf(o0, o1);
    float z = __expf(o0 - m) + __expf(o1 - m);
    out[tid] = __expf(s - m) * __builtin_amdgcn_rcpf(z);
}

// ---------- launch ----------
extern "C" void kernel_launch(void* const* d_in, const int* in_sizes, int n_in,
                              void* d_out, int out_size, void* d_ws, size_t ws_size,
                              hipStream_t stream) {
    const int*   tokens = (const int*)d_in[0];
    const float* emb    = (const float*)d_in[1];
    const float* W1     = (const float*)d_in[2];
    const float* U1     = (const float*)d_in[3];
    const float* b1     = (const float*)d_in[4];
    const float* W2     = (const float*)d_in[5];
    const float* U2     = (const float*)d_in[6];
    const float* b2     = (const float*)d_in[7];
    const float* Wd     = (const float*)d_in[8];
    const float* bd     = (const float*)d_in[9];
    float* out = (float*)d_out;

    char* ws = (char*)d_ws;
    float*          xw  = (float*)ws;                                  // 32 MB
    unsigned short* h1g = (unsigned short*)(ws + 33554432);            // 16 MB bf16 (+pad inside gap)
    char*           p   = ws + 33554432 + 16777216;                    // weights (unchanged offsets)
    unsigned short* W1t = (unsigned short*)p;            p += 512 * 256 * 2;
    unsigned short* W2t = (unsigned short*)p;            p += 256 * 256 * 2;
    unsigned short* U1t = (unsigned short*)p;            p += 256 * 256 * 2;
    unsigned short* U2t = (unsigned short*)p;            p += 256 * 256 * 2;
    float*          h2  = (float*)p;                     p += 64 * 256 * 4;
    int*            flags = (int*)p;                     // 64 ints

    const int M = 64 * 512;   // 32768

    // flags must be 0 before the pipeline kernel (graph-capture-safe async memset)
    hipMemsetAsync(flags, 0, 64 * sizeof(int), stream);

    // K0: weight/recurrence transposes to bf16 [N][K]
    transpose4<<<dim3(512, 4), 256, 0, stream>>>(W1, W2, U1, U2, W1t, W2t, U1t, U2t);

    // K1: xw1 = emb[tokens] @ W1 + b1   (gather fused, prefetch-pipelined)
    gemm_mfma<true><<<dim3(256 / 64, M / 64), 256, 0, stream>>>(
        emb, tokens, W1t, b1, xw, M, 256, 512);

    // K2: pipeline: dual-batch scan1 -> h1g -> stacked-[W2;U2] scan2 -> h2
    rnn_pipe2<<<96, 512, 0, stream>>>(xw, U1t, W2t, U2t, b2, h1g, flags, h2);

    // K3: softmax(h2 @ Wd + bd)
    head_kernel<<<1, 128, 0, stream>>>(h2, Wd, bd, out);
}

// Round 10
// 537.783 us; speedup vs baseline: 1.1979x; 1.1979x over previous
//
#include <hip/hip_runtime.h>

// ---------- types ----------
typedef __attribute__((ext_vector_type(8))) short bf16x8;
typedef __attribute__((ext_vector_type(4))) float f32x4;

static __device__ __forceinline__ unsigned short f2bf(float x) {
    unsigned int u = __float_as_uint(x);
    u += 0x7fffu + ((u >> 16) & 1u);   // RTNE, finite inputs
    return (unsigned short)(u >> 16);
}

static __device__ __forceinline__ float selq(const f32x4* a, int q) {
    return (q == 0) ? a[0][0] : (q == 1) ? a[1][0] : (q == 2) ? a[2][0] : a[3][0];
}

// Workgroup barrier WITHOUT vmcnt drain: LDS ordering only.
static __device__ __forceinline__ void barrier_lds_only() {
    __asm__ volatile("s_waitcnt lgkmcnt(0)\n\ts_barrier" ::: "memory");
}

// ---------- K0: four fp32->bf16 transposes in one launch ----------
__global__ void transpose4(const float* __restrict__ s0, const float* __restrict__ s1,
                           const float* __restrict__ s2, const float* __restrict__ s3,
                           unsigned short* __restrict__ d0, unsigned short* __restrict__ d1,
                           unsigned short* __restrict__ d2, unsigned short* __restrict__ d3) {
    int which = blockIdx.y;
    const float* src = which == 0 ? s0 : which == 1 ? s1 : which == 2 ? s2 : s3;
    unsigned short* dst = which == 0 ? d0 : which == 1 ? d1 : which == 2 ? d2 : d3;
    int K = (which == 0) ? 512 : 256;
    int idx = blockIdx.x * 256 + threadIdx.x;
    if (idx >= K * 256) return;
    int k = idx >> 8;          // N = 256
    int n = idx & 255;
    dst[n * K + k] = f2bf(src[idx]);
}

// ---------- K1: xw = emb[tokens] @ W1 + b1, FULL-N blocks ----------
// Grid = M/64 = 512 blocks (2/CU). Each block computes 64 rows x ALL 256 cols:
// A is gathered ONCE (64 MB total, was 256 MB with the 4-column-block grid) and
// f2bf'd once; B k-slices (256x32, 16 KB) staged in LDS; B total 256 KB is
// L2-resident across blocks. Fragment/output mapping identical to the proven gemm.
__global__ __launch_bounds__(256, 2) void gemm_gather(
    const float* __restrict__ emb, const int* __restrict__ tokens,
    const unsigned short* __restrict__ Bt,   // W1t [256][512] bf16 [n][k]
    const float* __restrict__ bias,
    float* __restrict__ C)                   // [M][256]
{
    const int m0  = blockIdx.x * 64;
    const int tid = threadIdx.x;

    __shared__ unsigned short As[64 * 40];     //  5 KB
    __shared__ unsigned short Bs[256 * 40];    // 20 KB
    __shared__ int tok[64];

    const int r  = tid >> 2;        // A row 0..63 (4 threads/row)
    const int c0 = (tid & 3) * 8;   // 8 floats each
    const int w  = tid >> 6;
    const int L  = tid & 63;
    const int ml = L & 15;
    const int q  = L >> 4;
    const int kq = q * 8;

    if (tid < 64) tok[tid] = tokens[m0 + tid];
    __syncthreads();

    const float* asrc = emb + (size_t)tok[r] * 512 + c0;
    const unsigned short* bsrc = Bt + (size_t)tid * 512;   // one B row per thread

    // prefetch tile 0
    float4 f0 = *(const float4*)asrc, f1 = *(const float4*)(asrc + 4);
    asrc += 32;
    uint4 bb0 = *(const uint4*)(bsrc +  0), bb1 = *(const uint4*)(bsrc +  8);
    uint4 bb2 = *(const uint4*)(bsrc + 16), bb3 = *(const uint4*)(bsrc + 24);
    bsrc += 32;

    f32x4 acc[16] = {};

    for (int k0 = 0; k0 < 512; k0 += 32) {
        unsigned short tmp[8];
        tmp[0]=f2bf(f0.x); tmp[1]=f2bf(f0.y); tmp[2]=f2bf(f0.z); tmp[3]=f2bf(f0.w);
        tmp[4]=f2bf(f1.x); tmp[5]=f2bf(f1.y); tmp[6]=f2bf(f1.z); tmp[7]=f2bf(f1.w);
        *(uint4*)&As[r * 40 + c0] = *(const uint4*)tmp;
        *(uint4*)&Bs[tid * 40 +  0] = bb0;
        *(uint4*)&Bs[tid * 40 +  8] = bb1;
        *(uint4*)&Bs[tid * 40 + 16] = bb2;
        *(uint4*)&Bs[tid * 40 + 24] = bb3;
        __syncthreads();

        if (k0 + 32 < 512) {   // prefetch next tile under this tile's MFMAs
            f0 = *(const float4*)asrc; f1 = *(const float4*)(asrc + 4); asrc += 32;
            bb0 = *(const uint4*)(bsrc +  0); bb1 = *(const uint4*)(bsrc +  8);
            bb2 = *(const uint4*)(bsrc + 16); bb3 = *(const uint4*)(bsrc + 24);
            bsrc += 32;
        }

        bf16x8 av = *(const bf16x8*)&As[(16 * w + ml) * 40 + kq];
#pragma unroll
        for (int ns = 0; ns < 16; ++ns) {
            bf16x8 bv = *(const bf16x8*)&Bs[(ns * 16 + ml) * 40 + kq];
            acc[ns] = __builtin_amdgcn_mfma_f32_16x16x32_bf16(av, bv, acc[ns], 0, 0, 0);
        }
        __syncthreads();
    }

#pragma unroll
    for (int ns = 0; ns < 16; ++ns) {
        int gn = ns * 16 + ml;
        float bv = bias[gn];
#pragma unroll
        for (int rr = 0; rr < 4; ++rr) {
            int gm = m0 + 16 * w + q * 4 + rr;
            C[(size_t)gm * 256 + gn] = acc[ns][rr] + bv;
        }
    }
}

// ---------- K2: r7's PASSING pipeline (pipe = 352 us measured) — verbatim ----------
// 128 blocks x 512 threads. Producer blocks 0..63: waves 0-3 ring-buffered scan1,
// waves 4-7 chunked GEMV p = h1@W2 + b2 once per 16 ticks (reads the ring half the
// scan isn't writing); drain at j==8, RELEASE flag at j==9. Consumer blocks
// 64..127: waves 0-3 scan2 on flag-gated pv[16]; waves 4-7 barrier-idle.
__global__ __launch_bounds__(512) void rnn_pipe(
    float* xw,                                // [64][512][256] f32: xw1, rows become p
    const unsigned short* __restrict__ U1t,   // [256][256] bf16 [n][k]
    const unsigned short* __restrict__ W2t,   // [256][256] bf16 [n][k]
    const unsigned short* __restrict__ U2t,   // [256][256] bf16 [n][k]
    const float* __restrict__ b2,             // [256]
    int* flags,                               // [64], zeroed before launch
    float* __restrict__ out_last)             // [64][256] f32
{
    const int bid = blockIdx.x;
    const int tid = threadIdx.x;
    const int w   = tid >> 6;       // 0..7
    const int rw  = w & 3;          // role sub-wave
    const int L   = tid & 63;
    const int col = tid & 255;
    const int q   = L >> 4;
    const int ml  = L & 15;

    __shared__ unsigned short ring[32][256];   // 16 KB h1 ring (producer) / hsh (consumer)

    if (bid < 64) {
        // ================= producer =================
        const int b = bid;
        int* flagp = flags + b;

        bf16x8 Bf[4][8];   // waves 0-3: U1; waves 4-7: W2 (ONE set per wave)
        const unsigned short* Bsrc = (w < 4) ? U1t : W2t;
#pragma unroll
        for (int i = 0; i < 4; ++i) {
            const unsigned short* up = Bsrc + (size_t)((rw * 4 + i) * 16 + ml) * 256 + q * 8;
#pragma unroll
            for (int kt = 0; kt < 8; ++kt)
                Bf[i][kt] = *(const bf16x8*)(up + kt * 32);
        }
        if (tid < 256) ring[31][tid] = 0;      // h1[-1] = 0

        const float* xpf = xw + (size_t)b * 512 * 256 + col;
        float xq[4];
        float b2v[4];
        if (w < 4) {
            xq[0] = xpf[0]; xq[1] = xpf[256]; xq[2] = xpf[512]; xq[3] = xpf[768];
            xpf += 4 * 256;
        } else {
#pragma unroll
            for (int i = 0; i < 4; ++i) b2v[i] = b2[rw * 64 + i * 16 + ml];
        }
        float* pb = xw + (size_t)b * 512 * 256;
        __syncthreads();

        for (int g = 0; g < 32; ++g) {
            const int half = g & 1;
#pragma unroll
            for (int j = 0; j < 16; ++j) {
                if (w < 4) {
                    // -------- scan tick t = 16g + j --------
                    const int slot_r = (j == 0) ? ((half ^ 1) * 16 + 15) : (half * 16 + j - 1);
                    bf16x8 af[8];
#pragma unroll
                    for (int kt = 0; kt < 8; ++kt)
                        af[kt] = *(const bf16x8*)&ring[slot_r][kt * 32 + q * 8];
                    float xnew = *xpf; xpf += 256;   // unconditional: overreads <=16KB of
                                                     // never-consumed workspace at the end
                    f32x4 accA[4] = {}, accB[4] = {};
#pragma unroll
                    for (int kt = 0; kt < 8; kt += 2) {
#pragma unroll
                        for (int i = 0; i < 4; ++i)
                            accA[i] = __builtin_amdgcn_mfma_f32_16x16x32_bf16(af[kt], Bf[i][kt], accA[i], 0, 0, 0);
#pragma unroll
                        for (int i = 0; i < 4; ++i)
                            accB[i] = __builtin_amdgcn_mfma_f32_16x16x32_bf16(af[kt + 1], Bf[i][kt + 1], accB[i], 0, 0, 0);
                    }
                    float z  = selq(accA, q) + selq(accB, q) + xq[j & 3];
                    float e  = __expf(2.f * z);       /* tanh(z) = 1 - 2/(e^{2z}+1) */
                    float hn = 1.f - 2.f * __builtin_amdgcn_rcpf(e + 1.f);
                    ring[half * 16 + j][col] = f2bf(hn);
                    xq[j & 3] = xnew;
                } else {
                    if (j == 0 && g > 0) {
                        // -------- chunked GEMV: rows 16(g-1)..16g-1 --------
                        const int half2 = half ^ 1;
                        const int t0 = (g - 1) * 16;
                        bf16x8 af[8];
#pragma unroll
                        for (int kt = 0; kt < 8; ++kt)
                            af[kt] = *(const bf16x8*)&ring[half2 * 16 + ml][kt * 32 + q * 8];
                        f32x4 acc[4] = {};
#pragma unroll
                        for (int kt = 0; kt < 8; ++kt)
#pragma unroll
                            for (int i = 0; i < 4; ++i)
                                acc[i] = __builtin_amdgcn_mfma_f32_16x16x32_bf16(af[kt], Bf[i][kt], acc[i], 0, 0, 0);
                        // C map (K1-verified): row = q*4+rr, col = rw*64+i*16+ml
                        float* ps = pb + (size_t)t0 * 256 + q * 1024 + rw * 64 + ml;
#pragma unroll
                        for (int i = 0; i < 4; ++i)
#pragma unroll
                            for (int rr = 0; rr < 4; ++rr)
                                ps[rr * 256 + i * 16] = acc[i][rr] + b2v[i];
                    }
                    if (j == 8 && g > 0)
                        asm volatile("s_waitcnt vmcnt(0)" ::: "memory");
                }
                if (j == 9 && g > 0 && tid == 0)
                    __hip_atomic_store(flagp, 16 * g, __ATOMIC_RELEASE, __HIP_MEMORY_SCOPE_AGENT);
                barrier_lds_only();
            }
        }
        // tail: chunk 31 (rows 496..511, ring slots 16..31)
        if (w >= 4) {
            bf16x8 af[8];
#pragma unroll
            for (int kt = 0; kt < 8; ++kt)
                af[kt] = *(const bf16x8*)&ring[16 + ml][kt * 32 + q * 8];
            f32x4 acc[4] = {};
#pragma unroll
            for (int kt = 0; kt < 8; ++kt)
#pragma unroll
                for (int i = 0; i < 4; ++i)
                    acc[i] = __builtin_amdgcn_mfma_f32_16x16x32_bf16(af[kt], Bf[i][kt], acc[i], 0, 0, 0);
            float* ps = pb + (size_t)496 * 256 + q * 1024 + rw * 64 + ml;
#pragma unroll
            for (int i = 0; i < 4; ++i)
#pragma unroll
                for (int rr = 0; rr < 4; ++rr)
                    ps[rr * 256 + i * 16] = acc[i][rr] + b2v[i];
            asm volatile("s_waitcnt vmcnt(0)" ::: "memory");
        }
        __builtin_amdgcn_s_barrier();
        if (tid == 0)
            __hip_atomic_store(flagp, 512, __ATOMIC_RELEASE, __HIP_MEMORY_SCOPE_AGENT);

    } else {
        // ================= consumer =================
        const int b = bid - 64;
        int* flagp = flags + b;
        unsigned short (*hsh)[256] = ring;

        bf16x8 Bf[4][8];   // U2 fragments (waves 4-7 load too; harmless, unused)
#pragma unroll
        for (int i = 0; i < 4; ++i) {
            const unsigned short* up = U2t + (size_t)((rw * 4 + i) * 16 + ml) * 256 + q * 8;
#pragma unroll
            for (int kt = 0; kt < 8; ++kt)
                Bf[i][kt] = *(const bf16x8*)(up + kt * 32);
        }
        if (tid < 256) hsh[0][tid] = 0;
        const float* pbc = xw + (size_t)b * 512 * 256 + col;
        float lastv = 0.f;
        __syncthreads();

#define CTICK(RP, PV)                                                                \
    {                                                                                \
        if (w < 4) {                                                                 \
            bf16x8 af[8];                                                            \
            _Pragma("unroll")                                                        \
            for (int kt = 0; kt < 8; ++kt)                                           \
                af[kt] = *(const bf16x8*)&hsh[RP][kt * 32 + q * 8];                  \
            f32x4 accA[4] = {}, accB[4] = {};                                        \
            _Pragma("unroll")                                                        \
            for (int kt = 0; kt < 8; kt += 2) {                                      \
                _Pragma("unroll")                                                    \
                for (int i = 0; i < 4; ++i)                                          \
                    accA[i] = __builtin_amdgcn_mfma_f32_16x16x32_bf16(af[kt], Bf[i][kt], accA[i], 0, 0, 0);       \
                _Pragma("unroll")                                                    \
                for (int i = 0; i < 4; ++i)                                          \
                    accB[i] = __builtin_amdgcn_mfma_f32_16x16x32_bf16(af[kt + 1], Bf[i][kt + 1], accB[i], 0, 0, 0); \
            }                                                                        \
            float z  = selq(accA, q) + selq(accB, q) + (PV);                         \
            float e  = __expf(2.f * z);                                              \
            float hn = 1.f - 2.f * __builtin_amdgcn_rcpf(e + 1.f);                   \
            lastv = hn;                                                              \
            hsh[(RP) ^ 1][col] = f2bf(hn);                                           \
        }                                                                            \
        barrier_lds_only();                                                          \
    }

        for (int c = 0; c < 32; ++c) {
            const int t0 = c * 16;
            if (tid == 0) {
                int it = 0;   // bounded spin: failure => wrong answer, never a hang
                while (__hip_atomic_load(flagp, __ATOMIC_ACQUIRE, __HIP_MEMORY_SCOPE_AGENT) < t0 + 16) {
                    __builtin_amdgcn_s_sleep(2);
                    if (++it > (1 << 17)) break;
                }
            }
            __syncthreads();
            float pv[16];
            if (w < 4) {
#pragma unroll
                for (int j = 0; j < 16; ++j)
                    pv[j] = pbc[(size_t)(t0 + j) << 8];
            }
            CTICK(0, pv[0])  CTICK(1, pv[1])  CTICK(0, pv[2])  CTICK(1, pv[3])
            CTICK(0, pv[4])  CTICK(1, pv[5])  CTICK(0, pv[6])  CTICK(1, pv[7])
            CTICK(0, pv[8])  CTICK(1, pv[9])  CTICK(0, pv[10]) CTICK(1, pv[11])
            CTICK(0, pv[12]) CTICK(1, pv[13]) CTICK(0, pv[14]) CTICK(1, pv[15])
        }
#undef CTICK

        if (w < 4) out_last[b * 256 + col] = lastv;
    }
}

// ---------- head: softmax(h2 @ Wd + bd) ----------
__global__ void head_kernel(const float* __restrict__ h2, const float* __restrict__ Wd,
                            const float* __restrict__ bd, float* __restrict__ out)
{
    int tid = threadIdx.x;         // 128 threads: b = tid>>1, c = tid&1
    int b = tid >> 1, c = tid & 1;
    float s = bd[c];
    for (int jj = 0; jj < 256; ++jj) s = fmaf(h2[b * 256 + jj], Wd[jj * 2 + c], s);
    __shared__ float lg[128];
    lg[tid] = s;
    __syncthreads();
    float o0 = lg[b * 2 + 0], o1 = lg[b * 2 + 1];
    float m = fmaxf(o0, o1);
    float z = __expf(o0 - m) + __expf(o1 - m);
    out[tid] = __expf(s - m) * __builtin_amdgcn_rcpf(z);
}

// ---------- launch ----------
extern "C" void kernel_launch(void* const* d_in, const int* in_sizes, int n_in,
                              void* d_out, int out_size, void* d_ws, size_t ws_size,
                              hipStream_t stream) {
    const int*   tokens = (const int*)d_in[0];
    const float* emb    = (const float*)d_in[1];
    const float* W1     = (const float*)d_in[2];
    const float* U1     = (const float*)d_in[3];
    const float* b1     = (const float*)d_in[4];
    const float* W2     = (const float*)d_in[5];
    const float* U2     = (const float*)d_in[6];
    const float* b2     = (const float*)d_in[7];
    const float* Wd     = (const float*)d_in[8];
    const float* bd     = (const float*)d_in[9];
    float* out = (float*)d_out;

    char* ws = (char*)d_ws;
    float*          xw  = (float*)ws;                                  // 32 MB (xw1 -> p in place)
    char*           p   = ws + 33554432 + 16777216;                    // weights (unchanged offsets)
    unsigned short* W1t = (unsigned short*)p;            p += 512 * 256 * 2;
    unsigned short* W2t = (unsigned short*)p;            p += 256 * 256 * 2;
    unsigned short* U1t = (unsigned short*)p;            p += 256 * 256 * 2;
    unsigned short* U2t = (unsigned short*)p;            p += 256 * 256 * 2;
    float*          h2  = (float*)p;                     p += 64 * 256 * 4;
    int*            flags = (int*)p;                     // 64 ints

    // flags must be 0 before the pipeline kernel (graph-capture-safe async memset)
    hipMemsetAsync(flags, 0, 64 * sizeof(int), stream);

    // K0: weight/recurrence transposes to bf16 [N][K]
    transpose4<<<dim3(512, 4), 256, 0, stream>>>(W1, W2, U1, U2, W1t, W2t, U1t, U2t);

    // K1: xw1 = emb[tokens] @ W1 + b1   (full-N blocks: A gathered once)
    gemm_gather<<<512, 256, 0, stream>>>(emb, tokens, W1t, b1, xw);

    // K2: r7's passing pipeline: scan1(+chunked GEMV) -> p in xw -> scan2 -> h2
    rnn_pipe<<<128, 512, 0, stream>>>(xw, U1t, W2t, U2t, b2, flags, h2);

    // K3: softmax(h2 @ Wd + bd)
    head_kernel<<<1, 128, 0, stream>>>(h2, Wd, bd, out);
}